// Round 9
// baseline (229.796 us; speedup 1.0000x reference)
//
#include <hip/hip_runtime.h>
#include <math.h>
#include <stdint.h>

// Transformer forward. R9 = R8 with the workspace-aliasing bug fixed:
// qb/kb/vb are 8 MiB each (2*8*4096*64 bf16) — R8 packed them at 4 MiB
// spacing, so q/k/v/pbf all overlapped (absmax 0.94). Offsets now 0/8/16/24 MiB.
// R8 structure (kept):
//  - 3-kernel chain: prep(+wf-GEMM +out=bo init) -> qkv-GEMM -> flash(+out-GEMM).
//  - wf GEMM (Wfused^T = (Wp@Wqkv)^T, 0.4 GF) inside prep, fp32->bf16 staged inline.
//  - out = attn@Wo + bo fused into flash epilogue: Wo^T head-slice staged into
//    the free KV[0], O round-trips Ps to A-layout, 64 MFMA/wave, fp32 atomicAdd
//    into d_out (pre-initialized to bo by prep).
//  - R5 flash main loop (32q/wave, dbuf prefetch, raw s_barrier + vmcnt(8)),
//    no-max exp2 softmax, ones-MFMA l, V stored transposed, S^T formulation.

typedef unsigned short u16;
typedef __attribute__((ext_vector_type(8))) __bf16 bf16x8;
typedef __attribute__((ext_vector_type(4))) __bf16 bf16x4;
typedef __attribute__((ext_vector_type(4))) float f32x4;

#define AS1 __attribute__((address_space(1)))
#define AS3 __attribute__((address_space(3)))

__device__ __forceinline__ void async16(const void* g, void* l) {
  __builtin_amdgcn_global_load_lds((const AS1 void*)g, (AS3 void*)l, 16, 0, 0);
}

__device__ __forceinline__ u16 f2bf(float f) {  // RNE fp32->bf16
  union { float f; unsigned u; } c; c.f = f;
  return (u16)((c.u + 0x7fffu + ((c.u >> 16) & 1u)) >> 16);
}

// ---------------- prep (one launch, block-range dispatch) ----------------
// [0,96):      wf GEMM  wfT[1536][256] = (Wp@Wqkv)^T, fp32 staged inline
// [96,120):    bias_fuse bfused[n] = bp@Wqkv[:,n] + bqkv[n]
// [120,632):   Wo [512][256] -> woT [256][512]
// [632,2680):  prompt fp32 -> bf16 (524288 float4)
// [2680,4728): out init: out[t][n] = bo[n] (524288 float4)
__global__ void prep_kernel(const float* __restrict__ prompt, u16* __restrict__ pbf,
                            const float* __restrict__ Wp, const float* __restrict__ Wqkv,
                            const float* __restrict__ Wo, u16* __restrict__ woT,
                            const float* __restrict__ bp, const float* __restrict__ bqkv,
                            float* __restrict__ bfused, u16* __restrict__ wfT,
                            const float* __restrict__ bo, float* __restrict__ outp) {
  __shared__ u16 Asf[64 * 40];   // [n][e], stride 40 (80B rows, 16B aligned)
  __shared__ u16 Bsf[64 * 32];   // [k][e]
  __shared__ float red[256];
  const int bid = blockIdx.x, tid = threadIdx.x;
  if (bid < 96) {                // wf GEMM: 4 k-tiles x 24 n-tiles of 64x64
    const int k0 = (bid & 3) * 64, n0 = (bid >> 2) * 64;
    const int lane = tid & 63, w = tid >> 6;
    const int wr = w >> 1, wc = w & 1;
    const int lr = lane >> 4, lc = lane & 15;
    f32x4 acc[2][2];
#pragma unroll
    for (int a = 0; a < 2; a++)
#pragma unroll
      for (int b = 0; b < 2; b++) acc[a][b] = (f32x4){0.f, 0.f, 0.f, 0.f};
    for (int e0 = 0; e0 < 512; e0 += 32) {
      {  // As[n][e] = bf16(Wqkv[e0+e][n0+n]) — coalesced row reads
        const int er = tid >> 3, ng = (tid & 7) * 8;
        float4 v1 = *(const float4*)&Wqkv[(e0 + er) * 1536 + n0 + ng];
        float4 v2 = *(const float4*)&Wqkv[(e0 + er) * 1536 + n0 + ng + 4];
        Asf[(ng + 0) * 40 + er] = f2bf(v1.x); Asf[(ng + 1) * 40 + er] = f2bf(v1.y);
        Asf[(ng + 2) * 40 + er] = f2bf(v1.z); Asf[(ng + 3) * 40 + er] = f2bf(v1.w);
        Asf[(ng + 4) * 40 + er] = f2bf(v2.x); Asf[(ng + 5) * 40 + er] = f2bf(v2.y);
        Asf[(ng + 6) * 40 + er] = f2bf(v2.z); Asf[(ng + 7) * 40 + er] = f2bf(v2.w);
      }
      {  // Bs[k][e] = bf16(Wp[k0+k][e0+e]) — coalesced, packed b128 write
        const int kr = tid >> 2, ec = (tid & 3) * 8;
        float4 w1 = *(const float4*)&Wp[(k0 + kr) * 512 + e0 + ec];
        float4 w2 = *(const float4*)&Wp[(k0 + kr) * 512 + e0 + ec + 4];
        u16 tmp[8] = {f2bf(w1.x), f2bf(w1.y), f2bf(w1.z), f2bf(w1.w),
                      f2bf(w2.x), f2bf(w2.y), f2bf(w2.z), f2bf(w2.w)};
        *(uint4*)&Bsf[kr * 32 + ec] = *(const uint4*)&tmp[0];
      }
      __syncthreads();
      bf16x8 af[2], bf2[2];
#pragma unroll
      for (int mi = 0; mi < 2; mi++)
        af[mi] = *(const bf16x8*)&Asf[(wr * 32 + mi * 16 + lc) * 40 + lr * 8];
#pragma unroll
      for (int nj = 0; nj < 2; nj++)
        bf2[nj] = *(const bf16x8*)&Bsf[(wc * 32 + nj * 16 + lc) * 32 + lr * 8];
#pragma unroll
      for (int mi = 0; mi < 2; mi++)
#pragma unroll
        for (int nj = 0; nj < 2; nj++)
          acc[mi][nj] = __builtin_amdgcn_mfma_f32_16x16x32_bf16(af[mi], bf2[nj], acc[mi][nj], 0, 0, 0);
      __syncthreads();
    }
#pragma unroll
    for (int mi = 0; mi < 2; mi++)
#pragma unroll
      for (int nj = 0; nj < 2; nj++)
#pragma unroll
        for (int r = 0; r < 4; r++)
          wfT[(n0 + wr * 32 + mi * 16 + 4 * lr + r) * 256 + k0 + wc * 32 + nj * 16 + lc] =
              f2bf(acc[mi][nj][r]);
  } else if (bid < 120) {        // bias fuse
    const int nloc = tid & 63, slice = tid >> 6;
    const int n = (bid - 96) * 64 + nloc;
    float s = 0.f;
#pragma unroll 8
    for (int e = slice * 128; e < slice * 128 + 128; e++) s += bp[e] * Wqkv[e * 1536 + n];
    red[tid] = s;
    __syncthreads();
    if (slice == 0)
      bfused[n] = red[nloc] + red[64 + nloc] + red[128 + nloc] + red[192 + nloc] + bqkv[n];
  } else if (bid < 632) {        // Wo^T
    int j = (bid - 120) * 256 + tid;
    int n = j >> 9, k = j & 511;
    woT[j] = f2bf(Wo[k * 256 + n]);
  } else if (bid < 2680) {       // prompt cvt
    int i = (bid - 632) * 256 + tid;
    float4 v = ((const float4*)prompt)[i];
    ushort4 o;
    o.x = f2bf(v.x); o.y = f2bf(v.y); o.z = f2bf(v.z); o.w = f2bf(v.w);
    ((ushort4*)pbf)[i] = o;
  } else {                       // out = bo (broadcast rows)
    int i = (bid - 2680) * 256 + tid;
    ((float4*)outp)[i] = ((const float4*)bo)[i & 63];
  }
}

// ---------------- GEMM: qkv = A[M,K](bf16) * Bt[N,K]^T(bf16) + bias ----------------
// 128x128 tile, BK=32, 4 waves (2x2). Double-buffered LDS; prefetch for k0+32
// issued during k0; raw s_barrier + vmcnt(4) keeps prefetch in flight.
// Epilogue: qkv split -> q(scaled)/k [b,h,t,d], v^T [b,h,d,t].
__global__ __launch_bounds__(256) void gemm_qkv(
    const u16* __restrict__ A, const u16* __restrict__ Bt, const float* __restrict__ bias,
    u16* __restrict__ qO, u16* __restrict__ kO, u16* __restrict__ vO, int K) {
  constexpr int TM = 128, TN = 128, MI = 4, NJ = 4;
  __shared__ __align__(16) u16 As[2][TM * 32];
  __shared__ __align__(16) u16 Bs[2][TN * 32];
  const int tid = threadIdx.x;
  const int lane = tid & 63, w = tid >> 6;
  const int wr = w >> 1, wc = w & 1;
  const int lr = lane >> 4, lc = lane & 15;
  const long tileM = (long)blockIdx.y * TM;
  const long tileN = (long)blockIdx.x * TN;

  f32x4 acc[MI][NJ];
#pragma unroll
  for (int a = 0; a < MI; a++)
#pragma unroll
    for (int b = 0; b < NJ; b++) acc[a][b] = (f32x4){0.f, 0.f, 0.f, 0.f};

  const int r0 = lane >> 2;
  const int blk = lane & 3;

  auto stage = [&](int buf, int k0) {
#pragma unroll
    for (int i = 0; i < 2; i++) {
      int r = w * 32 + i * 16 + r0;
      int g = (blk ^ ((r >> 1) & 3)) << 3;
      async16(A + (tileM + r) * (long)K + k0 + g, (void*)&As[buf][(w * 32 + i * 16) * 32]);
      async16(Bt + (tileN + r) * (long)K + k0 + g, (void*)&Bs[buf][(w * 32 + i * 16) * 32]);
    }
  };

  stage(0, 0);
  for (int k0 = 0; k0 < K; k0 += 32) {
    const int cur = (k0 >> 5) & 1;
    stage(cur ^ 1, (k0 + 32 < K) ? k0 + 32 : 0);  // last iter: dummy restage
    asm volatile("s_waitcnt vmcnt(4)" ::: "memory");
    asm volatile("s_barrier" ::: "memory");

    bf16x8 af[MI], bfv[NJ];
#pragma unroll
    for (int mi = 0; mi < MI; mi++) {
      int r = wr * 64 + mi * 16 + lc;
      af[mi] = *(const bf16x8*)&As[cur][r * 32 + ((lr ^ ((r >> 1) & 3)) << 3)];
    }
#pragma unroll
    for (int nj = 0; nj < NJ; nj++) {
      int r = wc * 64 + nj * 16 + lc;
      bfv[nj] = *(const bf16x8*)&Bs[cur][r * 32 + ((lr ^ ((r >> 1) & 3)) << 3)];
    }
#pragma unroll
    for (int mi = 0; mi < MI; mi++)
#pragma unroll
      for (int nj = 0; nj < NJ; nj++)
        acc[mi][nj] = __builtin_amdgcn_mfma_f32_16x16x32_bf16(af[mi], bfv[nj], acc[mi][nj], 0, 0, 0);
    asm volatile("s_barrier" ::: "memory");
  }

#pragma unroll
  for (int mi = 0; mi < MI; mi++)
#pragma unroll
    for (int nj = 0; nj < NJ; nj++) {
      long col = tileN + wc * 64 + nj * 16 + lc;
      float bcol = bias[col];
      long row0 = tileM + wr * 64 + mi * 16 + lr * 4;
      int sec = (int)(col >> 9);          // 0=q 1=k 2=v
      int c2 = (int)(col & 511);
      int h = c2 >> 6, d = c2 & 63;
      long pl = (row0 >> 12) * 8 + h;     // b*8+h
      long t0 = row0 & 4095;
      if (sec == 2) {                     // V transposed [b,h,d,t], packed 8B store
        ushort4 pk;
        pk.x = f2bf(acc[mi][nj][0] + bcol);
        pk.y = f2bf(acc[mi][nj][1] + bcol);
        pk.z = f2bf(acc[mi][nj][2] + bcol);
        pk.w = f2bf(acc[mi][nj][3] + bcol);
        *(ushort4*)&vO[(pl * 64 + d) * 4096 + t0] = pk;
      } else {
        u16* dst = sec ? kO : qO;
        const float sc = sec ? 1.f : 0.18033688f;  // q: 1/8 * log2(e)
#pragma unroll
        for (int r = 0; r < 4; r++)
          dst[((pl * 4096 + t0 + r) << 6) + d] = f2bf((acc[mi][nj][r] + bcol) * sc);
      }
    }
}

// ---------------- flash attention + fused out-GEMM ----------------
// Q,K bf16 [b*h,4096,64] (q pre-scaled by 0.125*log2e); VT bf16 [b*h,64,4096];
// woT bf16 [256][512]. Main loop = R5. Epilogue: O/l -> Ps (A-layout), Wo^T
// head slice -> KV[0] via async16, 64 MFMA/wave, fp32 atomicAdd into out
// (pre-initialized to bo by prep).
__global__ __launch_bounds__(256) void flash_attn(
    const u16* __restrict__ Q, const u16* __restrict__ Kg,
    const u16* __restrict__ VTg, const u16* __restrict__ WoTg,
    float* __restrict__ outp) {
  __shared__ __align__(16) u16 KV[2][16384];   // per buf: Ks[128*64] | Vt[64*128]
  __shared__ __align__(16) u16 Ps[4 * 2048];   // per-wave [32 q][64 key]

  const int tid = threadIdx.x, lane = tid & 63, w = tid >> 6;
  const int lr = lane >> 4, lc = lane & 15;
  const int plane = blockIdx.y;                // b*8+h
  const long pbase = (long)plane << 18;        // *4096*64
  const int qr0 = blockIdx.x * 128 + w * 32;

  bf16x8 bq[2][2];
#pragma unroll
  for (int qi = 0; qi < 2; qi++)
#pragma unroll
    for (int kk = 0; kk < 2; kk++)
      bq[qi][kk] = *(const bf16x8*)&Q[pbase + (long)(qr0 + qi * 16 + lc) * 64 + kk * 32 + lr * 8];

  bf16x8 ones;
#pragma unroll
  for (int u = 0; u < 8; u++) ones[u] = (__bf16)1.0f;

  f32x4 o[2][4], o1[2];
#pragma unroll
  for (int mi = 0; mi < 2; mi++) {
    o1[mi] = (f32x4){0.f, 0.f, 0.f, 0.f};
#pragma unroll
    for (int nj = 0; nj < 4; nj++) o[mi][nj] = (f32x4){0.f, 0.f, 0.f, 0.f};
  }

  const int krow = lane >> 3, kblk = lane & 7;
  const int vrow = lane >> 4, vblk = lane & 15;

  auto stage = [&](int buf, int j) {
    const u16* kS = Kg + pbase + (long)j * 8192;
    const u16* vS = VTg + pbase + j * 128;
#pragma unroll
    for (int i = 0; i < 4; i++) {
      int row = w * 32 + i * 8 + krow;
      async16(kS + (long)row * 64 + ((kblk ^ (row & 7)) << 3), (void*)&KV[buf][w * 2048 + i * 512]);
    }
#pragma unroll
    for (int i = 0; i < 4; i++) {
      int d = w * 16 + i * 4 + vrow;
      async16(vS + (long)d * 4096 + ((vblk ^ (d & 7)) << 3), (void*)&KV[buf][8192 + w * 2048 + i * 512]);
    }
  };

  stage(0, 0);
  for (int j = 0; j < 32; j++) {
    const int cur = j & 1;
    stage(cur ^ 1, (j + 1) & 31);  // j=31: dummy restage of tile 0
    asm volatile("s_waitcnt vmcnt(8)" ::: "memory");
    asm volatile("s_barrier" ::: "memory");

    const u16* Ks = &KV[cur][0];
    const u16* Vt = &KV[cur][8192];

    f32x4 s[8][2];
#pragma unroll
    for (int ki = 0; ki < 8; ki++)
#pragma unroll
      for (int qi = 0; qi < 2; qi++) s[ki][qi] = (f32x4){0.f, 0.f, 0.f, 0.f};
#pragma unroll
    for (int ki = 0; ki < 8; ki++) {
      bf16x8 ak[2];
#pragma unroll
      for (int kk = 0; kk < 2; kk++)
        ak[kk] = *(const bf16x8*)&Ks[(ki * 16 + lc) * 64 + (((kk * 4 + lr) ^ (lc & 7)) << 3)];
#pragma unroll
      for (int qi = 0; qi < 2; qi++)
#pragma unroll
        for (int kk = 0; kk < 2; kk++)
          s[ki][qi] = __builtin_amdgcn_mfma_f32_16x16x32_bf16(ak[kk], bq[qi][kk], s[ki][qi], 0, 0, 0);
    }

#pragma unroll
    for (int hh = 0; hh < 2; hh++) {
#pragma unroll
      for (int qi = 0; qi < 2; qi++) {
        const int pb = w * 2048 + (qi * 16 + lc) * 64 + 4 * (lr & 1);
#pragma unroll
        for (int kp = 0; kp < 4; kp++) {
          const int ki = 4 * hh + kp;
          bf16x4 pk;
          pk[0] = (__bf16)__builtin_amdgcn_exp2f(s[ki][qi][0]);
          pk[1] = (__bf16)__builtin_amdgcn_exp2f(s[ki][qi][1]);
          pk[2] = (__bf16)__builtin_amdgcn_exp2f(s[ki][qi][2]);
          pk[3] = (__bf16)__builtin_amdgcn_exp2f(s[ki][qi][3]);
          *(bf16x4*)&Ps[pb + (((2 * kp + (lr >> 1)) ^ (lc & 7)) << 3)] = pk;
        }
      }
#pragma unroll
      for (int kk = 0; kk < 2; kk++) {
        bf16x8 ap[2];
#pragma unroll
        for (int mi = 0; mi < 2; mi++)
          ap[mi] = *(const bf16x8*)&Ps[w * 2048 + (mi * 16 + lc) * 64 + (((4 * kk + lr) ^ (lc & 7)) << 3)];
#pragma unroll
        for (int nj = 0; nj < 4; nj++) {
          bf16x8 bv = *(const bf16x8*)&Vt[(nj * 16 + lc) * 128 + ((((hh * 2 + kk) * 4 + lr) ^ (lc & 7)) << 3)];
#pragma unroll
          for (int mi = 0; mi < 2; mi++)
            o[mi][nj] = __builtin_amdgcn_mfma_f32_16x16x32_bf16(ap[mi], bv, o[mi][nj], 0, 0, 0);
        }
#pragma unroll
        for (int mi = 0; mi < 2; mi++)
          o1[mi] = __builtin_amdgcn_mfma_f32_16x16x32_bf16(ap[mi], ones, o1[mi], 0, 0, 0);
      }
    }
    asm volatile("s_barrier" ::: "memory");
  }

  // ---- fused out-GEMM epilogue ----
  // drain the dummy prefetch into KV[0], then stage Wo^T head slice there
  asm volatile("s_waitcnt vmcnt(0)" ::: "memory");
  asm volatile("s_barrier" ::: "memory");
  {
    const u16* wS = WoTg + (plane & 7) * 64;   // woT[n][512], cols h*64..+63
#pragma unroll
    for (int i = 0; i < 8; i++) {
      int rowb = i * 32 + w * 8;
      int row = rowb + (lane >> 3);
      int src = ((lane & 7) ^ (row & 7)) << 3;
      async16(wS + (long)row * 512 + src, (void*)&KV[0][rowb * 64]);
    }
  }
  // O/l -> Ps in A-layout source form (per-wave region; same-wave W->R ordered)
#pragma unroll
  for (int mi = 0; mi < 2; mi++)
#pragma unroll
    for (int r = 0; r < 4; r++) {
      float inv = 1.f / o1[mi][r];
      int qloc = mi * 16 + 4 * lr + r;
#pragma unroll
      for (int nj = 0; nj < 4; nj++) {
        int d = nj * 16 + lc;
        Ps[w * 2048 + qloc * 64 + (((d >> 3) ^ (qloc & 7)) << 3) + (d & 7)] =
            f2bf(o[mi][nj][r] * inv);
      }
    }
  asm volatile("s_waitcnt vmcnt(0)" ::: "memory");
  asm volatile("s_barrier" ::: "memory");

  bf16x8 ap2[2][2];
#pragma unroll
  for (int mi = 0; mi < 2; mi++)
#pragma unroll
    for (int kk = 0; kk < 2; kk++)
      ap2[mi][kk] = *(const bf16x8*)&Ps[w * 2048 + (mi * 16 + lc) * 64 + (((kk * 4 + lr) ^ (lc & 7)) << 3)];
  const long tb = (long)(plane >> 3) * 4096 + qr0;
#pragma unroll
  for (int nb = 0; nb < 16; nb++) {
    f32x4 a2[2];
    a2[0] = (f32x4){0.f, 0.f, 0.f, 0.f};
    a2[1] = (f32x4){0.f, 0.f, 0.f, 0.f};
#pragma unroll
    for (int kk = 0; kk < 2; kk++) {
      bf16x8 bw = *(const bf16x8*)&KV[0][(nb * 16 + lc) * 64 + (((kk * 4 + lr) ^ (lc & 7)) << 3)];
#pragma unroll
      for (int mi = 0; mi < 2; mi++)
        a2[mi] = __builtin_amdgcn_mfma_f32_16x16x32_bf16(ap2[mi][kk], bw, a2[mi], 0, 0, 0);
    }
#pragma unroll
    for (int mi = 0; mi < 2; mi++)
#pragma unroll
      for (int r = 0; r < 4; r++)
        atomicAdd(&outp[(tb + mi * 16 + 4 * lr + r) * 256 + nb * 16 + lc], a2[mi][r]);
  }
}

// ---------------- launch ----------------
extern "C" void kernel_launch(void* const* d_in, const int* in_sizes, int n_in,
                              void* d_out, int out_size, void* d_ws, size_t ws_size,
                              hipStream_t stream) {
  const float* prompt = (const float*)d_in[0];
  const float* Wp = (const float*)d_in[1];
  const float* bp = (const float*)d_in[2];
  const float* Wqkv = (const float*)d_in[3];
  const float* bqkv = (const float*)d_in[4];
  const float* Wo = (const float*)d_in[5];
  const float* bo = (const float*)d_in[6];
  float* out = (float*)d_out;

  char* ws = (char*)d_ws;
  const size_t MiB = 1024 * 1024;
  u16* qb     = (u16*)(ws + 0);           // [b,h,t,d]  8 MiB
  u16* kb     = (u16*)(ws + 8 * MiB);     // [b,h,t,d]  8 MiB
  u16* vb     = (u16*)(ws + 16 * MiB);    // [b,h,d,t]  8 MiB (transposed)
  u16* pbf    = (u16*)(ws + 24 * MiB);    // [8192,256] bf16  4 MiB
  u16* woT    = (u16*)(ws + 28 * MiB);                  // [256,512]  256 KiB
  u16* wfT    = (u16*)(ws + 28 * MiB + 256 * 1024);     // [1536,256] 768 KiB
  float* bfused = (float*)(ws + 28 * MiB + 1024 * 1024);// [1536] fp32

  prep_kernel<<<dim3(4728), dim3(256), 0, stream>>>(
      prompt, pbf, Wp, Wqkv, Wo, woT, bp, bqkv, bfused, wfT, bo, out);

  // qkv = prompt @ Wfused + bfused -> q(scaled)/k [b,h,t,d], v^T [b,h,d,t]
  gemm_qkv<<<dim3(12, 64), dim3(256), 0, stream>>>(
      pbf, wfT, bfused, qb, kb, vb, 256);

  // flash attention + fused out-GEMM (atomic accumulate into out=bo)
  flash_attn<<<dim3(32, 16), dim3(256), 0, stream>>>(qb, kb, vb, woT, out);
}

// Round 10
// 210.781 us; speedup vs baseline: 1.0902x; 1.0902x over previous
//
#include <hip/hip_runtime.h>
#include <math.h>
#include <stdint.h>

// Transformer forward. R10 changes vs R9:
//  - Atomic out-GEMM fusion REVERTED (R9: WRITE_SIZE 8->64MB, flash +39us —
//    8 heads x RMW per out element). flash writes attnO bf16; separate
//    out-GEMM kernel (64x64 tile, 512 blocks, bias in epilogue, no out-init).
//  - Flash K-loop SOFTWARE-PIPELINED to break the per-iter wave convoy
//    (measured iter time ~= MFMA+VALU+LDS sum, not max): KV tile 64,
//    triple-buffered KV (3x16KB), double-buffered per-wave Ps (32KB) = 80KB.
//    Iter j: S(j) MFMAs, then PV(j-1) MFMAs interleaved with exp/pack(j) VALU.
//    vmcnt(4) BEFORE barrier (R5-proven ordering), 2 barriers/iter.
//  - Keeps: R9 merged prep (minus out-init), qkv GEMM, no-max exp2 softmax,
//    ones-MFMA l, V stored transposed, S^T formulation.

typedef unsigned short u16;
typedef __attribute__((ext_vector_type(8))) __bf16 bf16x8;
typedef __attribute__((ext_vector_type(4))) __bf16 bf16x4;
typedef __attribute__((ext_vector_type(4))) float f32x4;

#define AS1 __attribute__((address_space(1)))
#define AS3 __attribute__((address_space(3)))

__device__ __forceinline__ void async16(const void* g, void* l) {
  __builtin_amdgcn_global_load_lds((const AS1 void*)g, (AS3 void*)l, 16, 0, 0);
}

__device__ __forceinline__ u16 f2bf(float f) {  // RNE fp32->bf16
  union { float f; unsigned u; } c; c.f = f;
  return (u16)((c.u + 0x7fffu + ((c.u >> 16) & 1u)) >> 16);
}

// ---------------- prep (one launch, block-range dispatch) ----------------
// [0,96):     wf GEMM  wfT[1536][256] = (Wp@Wqkv)^T, fp32 staged inline
// [96,120):   bias_fuse bfused[n] = bp@Wqkv[:,n] + bqkv[n]
// [120,632):  Wo [512][256] -> woT [256][512]
// [632,2680): prompt fp32 -> bf16 (524288 float4)
__global__ void prep_kernel(const float* __restrict__ prompt, u16* __restrict__ pbf,
                            const float* __restrict__ Wp, const float* __restrict__ Wqkv,
                            const float* __restrict__ Wo, u16* __restrict__ woT,
                            const float* __restrict__ bp, const float* __restrict__ bqkv,
                            float* __restrict__ bfused, u16* __restrict__ wfT) {
  __shared__ u16 Asf[64 * 40];
  __shared__ u16 Bsf[64 * 32];
  __shared__ float red[256];
  const int bid = blockIdx.x, tid = threadIdx.x;
  if (bid < 96) {                // wf GEMM: 4 k-tiles x 24 n-tiles of 64x64
    const int k0 = (bid & 3) * 64, n0 = (bid >> 2) * 64;
    const int lane = tid & 63, w = tid >> 6;
    const int wr = w >> 1, wc = w & 1;
    const int lr = lane >> 4, lc = lane & 15;
    f32x4 acc[2][2];
#pragma unroll
    for (int a = 0; a < 2; a++)
#pragma unroll
      for (int b = 0; b < 2; b++) acc[a][b] = (f32x4){0.f, 0.f, 0.f, 0.f};
    for (int e0 = 0; e0 < 512; e0 += 32) {
      {  // As[n][e] = bf16(Wqkv[e0+e][n0+n])
        const int er = tid >> 3, ng = (tid & 7) * 8;
        float4 v1 = *(const float4*)&Wqkv[(e0 + er) * 1536 + n0 + ng];
        float4 v2 = *(const float4*)&Wqkv[(e0 + er) * 1536 + n0 + ng + 4];
        Asf[(ng + 0) * 40 + er] = f2bf(v1.x); Asf[(ng + 1) * 40 + er] = f2bf(v1.y);
        Asf[(ng + 2) * 40 + er] = f2bf(v1.z); Asf[(ng + 3) * 40 + er] = f2bf(v1.w);
        Asf[(ng + 4) * 40 + er] = f2bf(v2.x); Asf[(ng + 5) * 40 + er] = f2bf(v2.y);
        Asf[(ng + 6) * 40 + er] = f2bf(v2.z); Asf[(ng + 7) * 40 + er] = f2bf(v2.w);
      }
      {  // Bs[k][e] = bf16(Wp[k0+k][e0+e])
        const int kr = tid >> 2, ec = (tid & 3) * 8;
        float4 w1 = *(const float4*)&Wp[(k0 + kr) * 512 + e0 + ec];
        float4 w2 = *(const float4*)&Wp[(k0 + kr) * 512 + e0 + ec + 4];
        u16 tmp[8] = {f2bf(w1.x), f2bf(w1.y), f2bf(w1.z), f2bf(w1.w),
                      f2bf(w2.x), f2bf(w2.y), f2bf(w2.z), f2bf(w2.w)};
        *(uint4*)&Bsf[kr * 32 + ec] = *(const uint4*)&tmp[0];
      }
      __syncthreads();
      bf16x8 af[2], bf2[2];
#pragma unroll
      for (int mi = 0; mi < 2; mi++)
        af[mi] = *(const bf16x8*)&Asf[(wr * 32 + mi * 16 + lc) * 40 + lr * 8];
#pragma unroll
      for (int nj = 0; nj < 2; nj++)
        bf2[nj] = *(const bf16x8*)&Bsf[(wc * 32 + nj * 16 + lc) * 32 + lr * 8];
#pragma unroll
      for (int mi = 0; mi < 2; mi++)
#pragma unroll
        for (int nj = 0; nj < 2; nj++)
          acc[mi][nj] = __builtin_amdgcn_mfma_f32_16x16x32_bf16(af[mi], bf2[nj], acc[mi][nj], 0, 0, 0);
      __syncthreads();
    }
#pragma unroll
    for (int mi = 0; mi < 2; mi++)
#pragma unroll
      for (int nj = 0; nj < 2; nj++)
#pragma unroll
        for (int r = 0; r < 4; r++)
          wfT[(n0 + wr * 32 + mi * 16 + 4 * lr + r) * 256 + k0 + wc * 32 + nj * 16 + lc] =
              f2bf(acc[mi][nj][r]);
  } else if (bid < 120) {        // bias fuse
    const int nloc = tid & 63, slice = tid >> 6;
    const int n = (bid - 96) * 64 + nloc;
    float s = 0.f;
#pragma unroll 8
    for (int e = slice * 128; e < slice * 128 + 128; e++) s += bp[e] * Wqkv[e * 1536 + n];
    red[tid] = s;
    __syncthreads();
    if (slice == 0)
      bfused[n] = red[nloc] + red[64 + nloc] + red[128 + nloc] + red[192 + nloc] + bqkv[n];
  } else if (bid < 632) {        // Wo^T
    int j = (bid - 120) * 256 + tid;
    int n = j >> 9, k = j & 511;
    woT[j] = f2bf(Wo[k * 256 + n]);
  } else {                       // prompt cvt
    int i = (bid - 632) * 256 + tid;
    float4 v = ((const float4*)prompt)[i];
    ushort4 o;
    o.x = f2bf(v.x); o.y = f2bf(v.y); o.z = f2bf(v.z); o.w = f2bf(v.w);
    ((ushort4*)pbf)[i] = o;
  }
}

// ---------------- qkv GEMM (R9, unchanged) ----------------
__global__ __launch_bounds__(256) void gemm_qkv(
    const u16* __restrict__ A, const u16* __restrict__ Bt, const float* __restrict__ bias,
    u16* __restrict__ qO, u16* __restrict__ kO, u16* __restrict__ vO, int K) {
  constexpr int TM = 128, MI = 4, NJ = 4;
  __shared__ __align__(16) u16 As[2][TM * 32];
  __shared__ __align__(16) u16 Bs[2][TM * 32];
  const int tid = threadIdx.x;
  const int lane = tid & 63, w = tid >> 6;
  const int wr = w >> 1, wc = w & 1;
  const int lr = lane >> 4, lc = lane & 15;
  const long tileM = (long)blockIdx.y * 128;
  const long tileN = (long)blockIdx.x * 128;

  f32x4 acc[MI][NJ];
#pragma unroll
  for (int a = 0; a < MI; a++)
#pragma unroll
    for (int b = 0; b < NJ; b++) acc[a][b] = (f32x4){0.f, 0.f, 0.f, 0.f};

  const int r0 = lane >> 2;
  const int blk = lane & 3;

  auto stage = [&](int buf, int k0) {
#pragma unroll
    for (int i = 0; i < 2; i++) {
      int r = w * 32 + i * 16 + r0;
      int g = (blk ^ ((r >> 1) & 3)) << 3;
      async16(A + (tileM + r) * (long)K + k0 + g, (void*)&As[buf][(w * 32 + i * 16) * 32]);
      async16(Bt + (tileN + r) * (long)K + k0 + g, (void*)&Bs[buf][(w * 32 + i * 16) * 32]);
    }
  };

  stage(0, 0);
  for (int k0 = 0; k0 < K; k0 += 32) {
    const int cur = (k0 >> 5) & 1;
    stage(cur ^ 1, (k0 + 32 < K) ? k0 + 32 : 0);
    asm volatile("s_waitcnt vmcnt(4)" ::: "memory");
    asm volatile("s_barrier" ::: "memory");

    bf16x8 af[MI], bfv[NJ];
#pragma unroll
    for (int mi = 0; mi < MI; mi++) {
      int r = wr * 64 + mi * 16 + lc;
      af[mi] = *(const bf16x8*)&As[cur][r * 32 + ((lr ^ ((r >> 1) & 3)) << 3)];
    }
#pragma unroll
    for (int nj = 0; nj < NJ; nj++) {
      int r = wc * 64 + nj * 16 + lc;
      bfv[nj] = *(const bf16x8*)&Bs[cur][r * 32 + ((lr ^ ((r >> 1) & 3)) << 3)];
    }
#pragma unroll
    for (int mi = 0; mi < MI; mi++)
#pragma unroll
      for (int nj = 0; nj < NJ; nj++)
        acc[mi][nj] = __builtin_amdgcn_mfma_f32_16x16x32_bf16(af[mi], bfv[nj], acc[mi][nj], 0, 0, 0);
    asm volatile("s_barrier" ::: "memory");
  }

#pragma unroll
  for (int mi = 0; mi < MI; mi++)
#pragma unroll
    for (int nj = 0; nj < NJ; nj++) {
      long col = tileN + wc * 64 + nj * 16 + lc;
      float bcol = bias[col];
      long row0 = tileM + wr * 64 + mi * 16 + lr * 4;
      int sec = (int)(col >> 9);
      int c2 = (int)(col & 511);
      int h = c2 >> 6, d = c2 & 63;
      long pl = (row0 >> 12) * 8 + h;
      long t0 = row0 & 4095;
      if (sec == 2) {
        ushort4 pk;
        pk.x = f2bf(acc[mi][nj][0] + bcol);
        pk.y = f2bf(acc[mi][nj][1] + bcol);
        pk.z = f2bf(acc[mi][nj][2] + bcol);
        pk.w = f2bf(acc[mi][nj][3] + bcol);
        *(ushort4*)&vO[(pl * 64 + d) * 4096 + t0] = pk;
      } else {
        u16* dst = sec ? kO : qO;
        const float sc = sec ? 1.f : 0.18033688f;  // q: 1/8 * log2(e)
#pragma unroll
        for (int r = 0; r < 4; r++)
          dst[((pl * 4096 + t0 + r) << 6) + d] = f2bf((acc[mi][nj][r] + bcol) * sc);
      }
    }
}

// ---------------- flash attention (pipelined, KV64, tbuf KV + dbuf Ps) ----------------
// Q,K bf16 [b*h,4096,64] (q pre-scaled by 0.125*log2e); VT bf16 [b*h,64,4096].
// Block: 128 q (4 waves x 32). 64 tiles of 64 keys. Iter j: stage(j+1),
// vmcnt(4), barrier, S(j), PV(j-1) MFMAs interleaved with exp/pack(j) VALU,
// barrier. KV[3] 48KB, Ps[2] 32KB -> 80KB, 2 blocks/CU.
__global__ __launch_bounds__(256) void flash_attn(
    const u16* __restrict__ Q, const u16* __restrict__ Kg,
    const u16* __restrict__ VTg, u16* __restrict__ Og) {
  __shared__ __align__(16) u16 KV[3][8192];   // per buf: Ks[64*64] | Vt[64*64]
  __shared__ __align__(16) u16 Ps[2][8192];   // per buf, per wave [32 q][64 key]

  const int tid = threadIdx.x, lane = tid & 63, w = tid >> 6;
  const int lr = lane >> 4, lc = lane & 15;
  const int plane = blockIdx.y;                // b*8+h
  const long pbase = (long)plane << 18;        // *4096*64
  const int qr0 = blockIdx.x * 128 + w * 32;

  bf16x8 bq[2][2];
#pragma unroll
  for (int qi = 0; qi < 2; qi++)
#pragma unroll
    for (int kk = 0; kk < 2; kk++)
      bq[qi][kk] = *(const bf16x8*)&Q[pbase + (long)(qr0 + qi * 16 + lc) * 64 + kk * 32 + lr * 8];

  bf16x8 ones;
#pragma unroll
  for (int u = 0; u < 8; u++) ones[u] = (__bf16)1.0f;

  f32x4 o[2][4], o1[2];
#pragma unroll
  for (int mi = 0; mi < 2; mi++) {
    o1[mi] = (f32x4){0.f, 0.f, 0.f, 0.f};
#pragma unroll
    for (int nj = 0; nj < 4; nj++) o[mi][nj] = (f32x4){0.f, 0.f, 0.f, 0.f};
  }

  const int krow = lane >> 3, kblk = lane & 7;

  auto stage = [&](int buf, int j) {
    const u16* kS = Kg + pbase + (long)j * 4096;
    const u16* vS = VTg + pbase + (long)j * 64;
#pragma unroll
    for (int i = 0; i < 2; i++) {
      int row = w * 16 + i * 8 + krow;
      async16(kS + (long)row * 64 + ((kblk ^ (row & 7)) << 3),
              (void*)&KV[buf][(w * 16 + i * 8) * 64]);
    }
#pragma unroll
    for (int i = 0; i < 2; i++) {
      int d = w * 16 + i * 8 + krow;
      async16(vS + (long)d * 4096 + ((kblk ^ (d & 7)) << 3),
              (void*)&KV[buf][4096 + (w * 16 + i * 8) * 64]);
    }
  };

  f32x4 s[4][2];

  auto compute_S = [&](int buf) {
#pragma unroll
    for (int ki = 0; ki < 4; ki++)
#pragma unroll
      for (int qi = 0; qi < 2; qi++) s[ki][qi] = (f32x4){0.f, 0.f, 0.f, 0.f};
    const u16* Ks = &KV[buf][0];
#pragma unroll
    for (int ki = 0; ki < 4; ki++) {
      const int row = ki * 16 + lc;
      bf16x8 ak[2];
#pragma unroll
      for (int kk = 0; kk < 2; kk++)
        ak[kk] = *(const bf16x8*)&Ks[row * 64 + (((kk * 4 + lr) ^ (row & 7)) << 3)];
#pragma unroll
      for (int qi = 0; qi < 2; qi++)
#pragma unroll
        for (int kk = 0; kk < 2; kk++)
          s[ki][qi] = __builtin_amdgcn_mfma_f32_16x16x32_bf16(ak[kk], bq[qi][kk], s[ki][qi], 0, 0, 0);
    }
  };

  auto pack_P = [&](int pbuf) {
#pragma unroll
    for (int qi = 0; qi < 2; qi++) {
      const int pb = w * 2048 + (qi * 16 + lc) * 64 + 4 * (lr & 1);
#pragma unroll
      for (int ki = 0; ki < 4; ki++) {
        bf16x4 pk;
        pk[0] = (__bf16)__builtin_amdgcn_exp2f(s[ki][qi][0]);
        pk[1] = (__bf16)__builtin_amdgcn_exp2f(s[ki][qi][1]);
        pk[2] = (__bf16)__builtin_amdgcn_exp2f(s[ki][qi][2]);
        pk[3] = (__bf16)__builtin_amdgcn_exp2f(s[ki][qi][3]);
        *(bf16x4*)&Ps[pbuf][pb + (((2 * ki + (lr >> 1)) ^ (lc & 7)) << 3)] = pk;
      }
    }
  };

  auto compute_PV = [&](int pbuf, int vbuf) {
    const u16* Vt = &KV[vbuf][4096];
#pragma unroll
    for (int kk = 0; kk < 2; kk++) {
      bf16x8 ap[2];
#pragma unroll
      for (int mi = 0; mi < 2; mi++)
        ap[mi] = *(const bf16x8*)&Ps[pbuf][w * 2048 + (mi * 16 + lc) * 64 + (((kk * 4 + lr) ^ (lc & 7)) << 3)];
#pragma unroll
      for (int nj = 0; nj < 4; nj++) {
        const int row = nj * 16 + lc;
        bf16x8 bv = *(const bf16x8*)&Vt[row * 64 + (((kk * 4 + lr) ^ (row & 7)) << 3)];
#pragma unroll
        for (int mi = 0; mi < 2; mi++)
          o[mi][nj] = __builtin_amdgcn_mfma_f32_16x16x32_bf16(ap[mi], bv, o[mi][nj], 0, 0, 0);
      }
#pragma unroll
      for (int mi = 0; mi < 2; mi++)
        o1[mi] = __builtin_amdgcn_mfma_f32_16x16x32_bf16(ap[mi], ones, o1[mi], 0, 0, 0);
    }
  };

  stage(0, 0);
  stage(1, 1);
  // peeled j = 0
  asm volatile("s_waitcnt vmcnt(4)" ::: "memory");
  asm volatile("s_barrier" ::: "memory");
  compute_S(0);
  pack_P(0);
  asm volatile("s_barrier" ::: "memory");

  for (int j = 1; j < 64; j++) {
    const int bj = j % 3;
    stage((j + 1) % 3, (j + 1 < 64) ? j + 1 : 0);  // j=63: dummy restage
    asm volatile("s_waitcnt vmcnt(4)" ::: "memory");
    asm volatile("s_barrier" ::: "memory");
    compute_S(bj);                      // MFMA, tile j
    compute_PV((j - 1) & 1, (j - 1) % 3);  // MFMA, tile j-1 (interleaves with...)
    pack_P(j & 1);                      // ...VALU exp/pack, tile j
    asm volatile("s_barrier" ::: "memory");
  }
  compute_PV(63 & 1, 63 % 3);  // tail: PV(63) — Vt in buf 0, dummy went to buf 1

  const int bb = plane >> 3, h = plane & 7;
#pragma unroll
  for (int mi = 0; mi < 2; mi++)
#pragma unroll
    for (int r = 0; r < 4; r++) {
      float inv = 1.f / o1[mi][r];
      long t = qr0 + mi * 16 + 4 * lr + r;
#pragma unroll
      for (int nj = 0; nj < 4; nj++)
        Og[(((long)(bb * 4096 + t) * 8 + h) << 6) + nj * 16 + lc] = f2bf(o[mi][nj][r] * inv);
    }
}

// ---------------- out GEMM: out[8192,256] = attnO[8192,512] @ woT^T + bo ----------------
// 64x64 tile, 512 blocks (2/CU), dbuf prefetch K-loop, fp32 store + bias.
__global__ __launch_bounds__(256) void gemm_out(
    const u16* __restrict__ A, const u16* __restrict__ Bt, const float* __restrict__ bias,
    float* __restrict__ outf) {
  constexpr int K = 512;
  __shared__ __align__(16) u16 As[2][64 * 32];
  __shared__ __align__(16) u16 Bs[2][64 * 32];
  const int tid = threadIdx.x;
  const int lane = tid & 63, w = tid >> 6;
  const int wr = w >> 1, wc = w & 1;
  const int lr = lane >> 4, lc = lane & 15;
  const long tileM = (long)blockIdx.y * 64;
  const long tileN = (long)blockIdx.x * 64;

  f32x4 acc[2][2];
#pragma unroll
  for (int a = 0; a < 2; a++)
#pragma unroll
    for (int b = 0; b < 2; b++) acc[a][b] = (f32x4){0.f, 0.f, 0.f, 0.f};

  const int r0 = lane >> 2;
  const int blk = lane & 3;

  auto stage = [&](int buf, int k0) {
    int r = w * 16 + r0;
    int g = (blk ^ ((r >> 1) & 3)) << 3;
    async16(A + (tileM + r) * (long)K + k0 + g, (void*)&As[buf][(w * 16) * 32]);
    async16(Bt + (tileN + r) * (long)K + k0 + g, (void*)&Bs[buf][(w * 16) * 32]);
  };

  stage(0, 0);
  for (int k0 = 0; k0 < K; k0 += 32) {
    const int cur = (k0 >> 5) & 1;
    stage(cur ^ 1, (k0 + 32 < K) ? k0 + 32 : 0);
    asm volatile("s_waitcnt vmcnt(2)" ::: "memory");
    asm volatile("s_barrier" ::: "memory");

    bf16x8 af[2], bfv[2];
#pragma unroll
    for (int mi = 0; mi < 2; mi++) {
      int r = wr * 32 + mi * 16 + lc;
      af[mi] = *(const bf16x8*)&As[cur][r * 32 + ((lr ^ ((r >> 1) & 3)) << 3)];
    }
#pragma unroll
    for (int nj = 0; nj < 2; nj++) {
      int r = wc * 32 + nj * 16 + lc;
      bfv[nj] = *(const bf16x8*)&Bs[cur][r * 32 + ((lr ^ ((r >> 1) & 3)) << 3)];
    }
#pragma unroll
    for (int mi = 0; mi < 2; mi++)
#pragma unroll
      for (int nj = 0; nj < 2; nj++)
        acc[mi][nj] = __builtin_amdgcn_mfma_f32_16x16x32_bf16(af[mi], bfv[nj], acc[mi][nj], 0, 0, 0);
    asm volatile("s_barrier" ::: "memory");
  }

#pragma unroll
  for (int mi = 0; mi < 2; mi++)
#pragma unroll
    for (int nj = 0; nj < 2; nj++) {
      long col = tileN + wc * 32 + nj * 16 + lc;
      float bcol = bias[col];
      long row0 = tileM + wr * 32 + mi * 16 + lr * 4;
#pragma unroll
      for (int r = 0; r < 4; r++)
        outf[(row0 + r) * 256 + col] = acc[mi][nj][r] + bcol;
    }
}

// ---------------- launch ----------------
extern "C" void kernel_launch(void* const* d_in, const int* in_sizes, int n_in,
                              void* d_out, int out_size, void* d_ws, size_t ws_size,
                              hipStream_t stream) {
  const float* prompt = (const float*)d_in[0];
  const float* Wp = (const float*)d_in[1];
  const float* bp = (const float*)d_in[2];
  const float* Wqkv = (const float*)d_in[3];
  const float* bqkv = (const float*)d_in[4];
  const float* Wo = (const float*)d_in[5];
  const float* bo = (const float*)d_in[6];
  float* out = (float*)d_out;

  char* ws = (char*)d_ws;
  const size_t MiB = 1024 * 1024;
  u16* qb     = (u16*)(ws + 0);           // [b,h,t,d]  8 MiB
  u16* kb     = (u16*)(ws + 8 * MiB);     // [b,h,t,d]  8 MiB
  u16* vb     = (u16*)(ws + 16 * MiB);    // [b,h,d,t]  8 MiB (transposed)
  u16* pbf    = (u16*)(ws + 24 * MiB);    // [8192,256] bf16  4 MiB
  u16* attnO  = (u16*)(ws + 28 * MiB);    // [8192,512] bf16  8 MiB
  u16* woT    = (u16*)(ws + 36 * MiB);                  // [256,512]  256 KiB
  u16* wfT    = (u16*)(ws + 36 * MiB + 256 * 1024);     // [1536,256] 768 KiB
  float* bfused = (float*)(ws + 36 * MiB + 1024 * 1024);// [1536] fp32

  prep_kernel<<<dim3(2680), dim3(256), 0, stream>>>(
      prompt, pbf, Wp, Wqkv, Wo, woT, bp, bqkv, bfused, wfT);

  // qkv = prompt @ Wfused + bfused -> q(scaled)/k [b,h,t,d], v^T [b,h,d,t]
  gemm_qkv<<<dim3(12, 64), dim3(256), 0, stream>>>(
      pbf, wfT, bfused, qb, kb, vb, 256);

  // flash attention -> attn_out bf16 [b,t,h*d]
  flash_attn<<<dim3(32, 16), dim3(256), 0, stream>>>(qb, kb, vb, attnO);

  // out = attn @ Wo + bo (fp32)
  gemm_out<<<dim3(4, 128), dim3(256), 0, stream>>>(attnO, woT, bo, out);
}

// Round 11
// 207.467 us; speedup vs baseline: 1.1076x; 1.0160x over previous
//
#include <hip/hip_runtime.h>
#include <math.h>
#include <stdint.h>

// Transformer forward. R11 changes vs R10:
//  - R10's explicit pipeline REVERTED (2x barriers at same TLP: 101->116us).
//  - Flash SPLIT-K=2: grid (32,16,2); each block does 32 KV64-iters over half
//    the keys (R7-style sequential body, 2 barriers/iter). LDS = dbuf KV
//    2x16KB + Ps 16KB = 48KB -> 3 blocks/CU = 12 waves/CU (was 2 blocks, 8
//    waves). Split-K is LDS-traffic-neutral (32q/wave kept); no-max softmax
//    makes partials mergeable: O=(O0+O1)/(l0+l1).
//  - Flash writes bf16 O-partials (no divide) + fp32 l-partials; reduce kernel
//    combines IN-PLACE into Op0 (== attnO layout, fed to out-GEMM). lp overlays
//    dead pbf; no new big buffers (ws ~45 MiB).
//  - Keeps: merged prep (wf-GEMM + bias_fuse + Wo^T + prompt cvt), qkv GEMM,
//    out GEMM, no-max exp2 softmax, ones-MFMA l, V transposed, S^T form.

typedef unsigned short u16;
typedef __attribute__((ext_vector_type(8))) __bf16 bf16x8;
typedef __attribute__((ext_vector_type(4))) __bf16 bf16x4;
typedef __attribute__((ext_vector_type(4))) float f32x4;

#define AS1 __attribute__((address_space(1)))
#define AS3 __attribute__((address_space(3)))

__device__ __forceinline__ void async16(const void* g, void* l) {
  __builtin_amdgcn_global_load_lds((const AS1 void*)g, (AS3 void*)l, 16, 0, 0);
}

__device__ __forceinline__ u16 f2bf(float f) {  // RNE fp32->bf16
  union { float f; unsigned u; } c; c.f = f;
  return (u16)((c.u + 0x7fffu + ((c.u >> 16) & 1u)) >> 16);
}

__device__ __forceinline__ float bf2f(u16 u) {
  union { unsigned x; float f; } z; z.x = (unsigned)u << 16; return z.f;
}

// ---------------- prep (one launch, block-range dispatch) ----------------
// [0,96):     wf GEMM  wfT[1536][256] = (Wp@Wqkv)^T, fp32 staged inline
// [96,120):   bias_fuse bfused[n] = bp@Wqkv[:,n] + bqkv[n]
// [120,632):  Wo [512][256] -> woT [256][512]
// [632,2680): prompt fp32 -> bf16 (524288 float4)
__global__ void prep_kernel(const float* __restrict__ prompt, u16* __restrict__ pbf,
                            const float* __restrict__ Wp, const float* __restrict__ Wqkv,
                            const float* __restrict__ Wo, u16* __restrict__ woT,
                            const float* __restrict__ bp, const float* __restrict__ bqkv,
                            float* __restrict__ bfused, u16* __restrict__ wfT) {
  __shared__ u16 Asf[64 * 40];
  __shared__ u16 Bsf[64 * 32];
  __shared__ float red[256];
  const int bid = blockIdx.x, tid = threadIdx.x;
  if (bid < 96) {                // wf GEMM: 4 k-tiles x 24 n-tiles of 64x64
    const int k0 = (bid & 3) * 64, n0 = (bid >> 2) * 64;
    const int lane = tid & 63, w = tid >> 6;
    const int wr = w >> 1, wc = w & 1;
    const int lr = lane >> 4, lc = lane & 15;
    f32x4 acc[2][2];
#pragma unroll
    for (int a = 0; a < 2; a++)
#pragma unroll
      for (int b = 0; b < 2; b++) acc[a][b] = (f32x4){0.f, 0.f, 0.f, 0.f};
    for (int e0 = 0; e0 < 512; e0 += 32) {
      {  // As[n][e] = bf16(Wqkv[e0+e][n0+n])
        const int er = tid >> 3, ng = (tid & 7) * 8;
        float4 v1 = *(const float4*)&Wqkv[(e0 + er) * 1536 + n0 + ng];
        float4 v2 = *(const float4*)&Wqkv[(e0 + er) * 1536 + n0 + ng + 4];
        Asf[(ng + 0) * 40 + er] = f2bf(v1.x); Asf[(ng + 1) * 40 + er] = f2bf(v1.y);
        Asf[(ng + 2) * 40 + er] = f2bf(v1.z); Asf[(ng + 3) * 40 + er] = f2bf(v1.w);
        Asf[(ng + 4) * 40 + er] = f2bf(v2.x); Asf[(ng + 5) * 40 + er] = f2bf(v2.y);
        Asf[(ng + 6) * 40 + er] = f2bf(v2.z); Asf[(ng + 7) * 40 + er] = f2bf(v2.w);
      }
      {  // Bs[k][e] = bf16(Wp[k0+k][e0+e])
        const int kr = tid >> 2, ec = (tid & 3) * 8;
        float4 w1 = *(const float4*)&Wp[(k0 + kr) * 512 + e0 + ec];
        float4 w2 = *(const float4*)&Wp[(k0 + kr) * 512 + e0 + ec + 4];
        u16 tmp[8] = {f2bf(w1.x), f2bf(w1.y), f2bf(w1.z), f2bf(w1.w),
                      f2bf(w2.x), f2bf(w2.y), f2bf(w2.z), f2bf(w2.w)};
        *(uint4*)&Bsf[kr * 32 + ec] = *(const uint4*)&tmp[0];
      }
      __syncthreads();
      bf16x8 af[2], bf2[2];
#pragma unroll
      for (int mi = 0; mi < 2; mi++)
        af[mi] = *(const bf16x8*)&Asf[(wr * 32 + mi * 16 + lc) * 40 + lr * 8];
#pragma unroll
      for (int nj = 0; nj < 2; nj++)
        bf2[nj] = *(const bf16x8*)&Bsf[(wc * 32 + nj * 16 + lc) * 32 + lr * 8];
#pragma unroll
      for (int mi = 0; mi < 2; mi++)
#pragma unroll
        for (int nj = 0; nj < 2; nj++)
          acc[mi][nj] = __builtin_amdgcn_mfma_f32_16x16x32_bf16(af[mi], bf2[nj], acc[mi][nj], 0, 0, 0);
      __syncthreads();
    }
#pragma unroll
    for (int mi = 0; mi < 2; mi++)
#pragma unroll
      for (int nj = 0; nj < 2; nj++)
#pragma unroll
        for (int r = 0; r < 4; r++)
          wfT[(n0 + wr * 32 + mi * 16 + 4 * lr + r) * 256 + k0 + wc * 32 + nj * 16 + lc] =
              f2bf(acc[mi][nj][r]);
  } else if (bid < 120) {        // bias fuse
    const int nloc = tid & 63, slice = tid >> 6;
    const int n = (bid - 96) * 64 + nloc;
    float s = 0.f;
#pragma unroll 8
    for (int e = slice * 128; e < slice * 128 + 128; e++) s += bp[e] * Wqkv[e * 1536 + n];
    red[tid] = s;
    __syncthreads();
    if (slice == 0)
      bfused[n] = red[nloc] + red[64 + nloc] + red[128 + nloc] + red[192 + nloc] + bqkv[n];
  } else if (bid < 632) {        // Wo^T
    int j = (bid - 120) * 256 + tid;
    int n = j >> 9, k = j & 511;
    woT[j] = f2bf(Wo[k * 256 + n]);
  } else {                       // prompt cvt
    int i = (bid - 632) * 256 + tid;
    float4 v = ((const float4*)prompt)[i];
    ushort4 o;
    o.x = f2bf(v.x); o.y = f2bf(v.y); o.z = f2bf(v.z); o.w = f2bf(v.w);
    ((ushort4*)pbf)[i] = o;
  }
}

// ---------------- qkv GEMM (unchanged) ----------------
__global__ __launch_bounds__(256) void gemm_qkv(
    const u16* __restrict__ A, const u16* __restrict__ Bt, const float* __restrict__ bias,
    u16* __restrict__ qO, u16* __restrict__ kO, u16* __restrict__ vO, int K) {
  constexpr int TM = 128, MI = 4, NJ = 4;
  __shared__ __align__(16) u16 As[2][TM * 32];
  __shared__ __align__(16) u16 Bs[2][TM * 32];
  const int tid = threadIdx.x;
  const int lane = tid & 63, w = tid >> 6;
  const int wr = w >> 1, wc = w & 1;
  const int lr = lane >> 4, lc = lane & 15;
  const long tileM = (long)blockIdx.y * 128;
  const long tileN = (long)blockIdx.x * 128;

  f32x4 acc[MI][NJ];
#pragma unroll
  for (int a = 0; a < MI; a++)
#pragma unroll
    for (int b = 0; b < NJ; b++) acc[a][b] = (f32x4){0.f, 0.f, 0.f, 0.f};

  const int r0 = lane >> 2;
  const int blk = lane & 3;

  auto stage = [&](int buf, int k0) {
#pragma unroll
    for (int i = 0; i < 2; i++) {
      int r = w * 32 + i * 16 + r0;
      int g = (blk ^ ((r >> 1) & 3)) << 3;
      async16(A + (tileM + r) * (long)K + k0 + g, (void*)&As[buf][(w * 32 + i * 16) * 32]);
      async16(Bt + (tileN + r) * (long)K + k0 + g, (void*)&Bs[buf][(w * 32 + i * 16) * 32]);
    }
  };

  stage(0, 0);
  for (int k0 = 0; k0 < K; k0 += 32) {
    const int cur = (k0 >> 5) & 1;
    stage(cur ^ 1, (k0 + 32 < K) ? k0 + 32 : 0);
    asm volatile("s_waitcnt vmcnt(4)" ::: "memory");
    asm volatile("s_barrier" ::: "memory");

    bf16x8 af[MI], bfv[NJ];
#pragma unroll
    for (int mi = 0; mi < MI; mi++) {
      int r = wr * 64 + mi * 16 + lc;
      af[mi] = *(const bf16x8*)&As[cur][r * 32 + ((lr ^ ((r >> 1) & 3)) << 3)];
    }
#pragma unroll
    for (int nj = 0; nj < NJ; nj++) {
      int r = wc * 64 + nj * 16 + lc;
      bfv[nj] = *(const bf16x8*)&Bs[cur][r * 32 + ((lr ^ ((r >> 1) & 3)) << 3)];
    }
#pragma unroll
    for (int mi = 0; mi < MI; mi++)
#pragma unroll
      for (int nj = 0; nj < NJ; nj++)
        acc[mi][nj] = __builtin_amdgcn_mfma_f32_16x16x32_bf16(af[mi], bfv[nj], acc[mi][nj], 0, 0, 0);
    asm volatile("s_barrier" ::: "memory");
  }

#pragma unroll
  for (int mi = 0; mi < MI; mi++)
#pragma unroll
    for (int nj = 0; nj < NJ; nj++) {
      long col = tileN + wc * 64 + nj * 16 + lc;
      float bcol = bias[col];
      long row0 = tileM + wr * 64 + mi * 16 + lr * 4;
      int sec = (int)(col >> 9);
      int c2 = (int)(col & 511);
      int h = c2 >> 6, d = c2 & 63;
      long pl = (row0 >> 12) * 8 + h;
      long t0 = row0 & 4095;
      if (sec == 2) {
        ushort4 pk;
        pk.x = f2bf(acc[mi][nj][0] + bcol);
        pk.y = f2bf(acc[mi][nj][1] + bcol);
        pk.z = f2bf(acc[mi][nj][2] + bcol);
        pk.w = f2bf(acc[mi][nj][3] + bcol);
        *(ushort4*)&vO[(pl * 64 + d) * 4096 + t0] = pk;
      } else {
        u16* dst = sec ? kO : qO;
        const float sc = sec ? 1.f : 0.18033688f;  // q: 1/8 * log2(e)
#pragma unroll
        for (int r = 0; r < 4; r++)
          dst[((pl * 4096 + t0 + r) << 6) + d] = f2bf((acc[mi][nj][r] + bcol) * sc);
      }
    }
}

// ---------------- flash attention (split-K=2, KV64, 48KB LDS -> 3 blocks/CU) ----------------
// Q,K bf16 [b*h,4096,64] (q pre-scaled by 0.125*log2e); VT bf16 [b*h,64,4096].
// Block (qtile, plane, split): 128 q x 2048 keys, 32 KV64-iters, R7-style body.
// Writes bf16 O-partial (no divide) + fp32 l-partial; reduce combines.
__global__ __launch_bounds__(256) void flash_attn(
    const u16* __restrict__ Q, const u16* __restrict__ Kg,
    const u16* __restrict__ VTg, u16* __restrict__ Op, float* __restrict__ lp) {
  __shared__ __align__(16) u16 KV[2][8192];   // per buf: Ks[64*64] | Vt[64*64]
  __shared__ __align__(16) u16 Ps[4 * 2048];  // per-wave [32 q][64 key]

  const int tid = threadIdx.x, lane = tid & 63, w = tid >> 6;
  const int lr = lane >> 4, lc = lane & 15;
  const int plane = blockIdx.y;                // b*8+h
  const int split = blockIdx.z;                // 0/1: keys [0,2048) / [2048,4096)
  const long pbase = (long)plane << 18;        // *4096*64
  const int qr0 = blockIdx.x * 128 + w * 32;
  const int tj0 = split * 32;                  // first KV64 tile index

  bf16x8 bq[2][2];
#pragma unroll
  for (int qi = 0; qi < 2; qi++)
#pragma unroll
    for (int kk = 0; kk < 2; kk++)
      bq[qi][kk] = *(const bf16x8*)&Q[pbase + (long)(qr0 + qi * 16 + lc) * 64 + kk * 32 + lr * 8];

  bf16x8 ones;
#pragma unroll
  for (int u = 0; u < 8; u++) ones[u] = (__bf16)1.0f;

  f32x4 o[2][4], o1[2];
#pragma unroll
  for (int mi = 0; mi < 2; mi++) {
    o1[mi] = (f32x4){0.f, 0.f, 0.f, 0.f};
#pragma unroll
    for (int nj = 0; nj < 4; nj++) o[mi][nj] = (f32x4){0.f, 0.f, 0.f, 0.f};
  }

  const int krow = lane >> 3, kblk = lane & 7;

  auto stage = [&](int buf, int tj) {
    const u16* kS = Kg + pbase + (long)tj * 4096;
    const u16* vS = VTg + pbase + (long)tj * 64;
#pragma unroll
    for (int i = 0; i < 2; i++) {
      int row = w * 16 + i * 8 + krow;
      async16(kS + (long)row * 64 + ((kblk ^ (row & 7)) << 3),
              (void*)&KV[buf][(w * 16 + i * 8) * 64]);
    }
#pragma unroll
    for (int i = 0; i < 2; i++) {
      int d = w * 16 + i * 8 + krow;
      async16(vS + (long)d * 4096 + ((kblk ^ (d & 7)) << 3),
              (void*)&KV[buf][4096 + (w * 16 + i * 8) * 64]);
    }
  };

  stage(0, tj0);
  for (int j = 0; j < 32; j++) {
    const int cur = j & 1;
    stage(cur ^ 1, (j + 1 < 32) ? tj0 + j + 1 : tj0);  // j=31: dummy restage
    asm volatile("s_waitcnt vmcnt(4)" ::: "memory");
    asm volatile("s_barrier" ::: "memory");

    const u16* Ks = &KV[cur][0];
    const u16* Vt = &KV[cur][4096];

    // S^T tile: [64 key][32 q] per wave
    f32x4 s[4][2];
#pragma unroll
    for (int ki = 0; ki < 4; ki++)
#pragma unroll
      for (int qi = 0; qi < 2; qi++) s[ki][qi] = (f32x4){0.f, 0.f, 0.f, 0.f};
#pragma unroll
    for (int ki = 0; ki < 4; ki++) {
      const int row = ki * 16 + lc;
      bf16x8 ak[2];
#pragma unroll
      for (int kk = 0; kk < 2; kk++)
        ak[kk] = *(const bf16x8*)&Ks[row * 64 + (((kk * 4 + lr) ^ (row & 7)) << 3)];
#pragma unroll
      for (int qi = 0; qi < 2; qi++)
#pragma unroll
        for (int kk = 0; kk < 2; kk++)
          s[ki][qi] = __builtin_amdgcn_mfma_f32_16x16x32_bf16(ak[kk], bq[qi][kk], s[ki][qi], 0, 0, 0);
    }

    // p = exp2(s) -> Ps (per-wave; same-wave LDS W->R is in-order)
#pragma unroll
    for (int qi = 0; qi < 2; qi++) {
      const int pb = w * 2048 + (qi * 16 + lc) * 64 + 4 * (lr & 1);
#pragma unroll
      for (int ki = 0; ki < 4; ki++) {
        bf16x4 pk;
        pk[0] = (__bf16)__builtin_amdgcn_exp2f(s[ki][qi][0]);
        pk[1] = (__bf16)__builtin_amdgcn_exp2f(s[ki][qi][1]);
        pk[2] = (__bf16)__builtin_amdgcn_exp2f(s[ki][qi][2]);
        pk[3] = (__bf16)__builtin_amdgcn_exp2f(s[ki][qi][3]);
        *(bf16x4*)&Ps[pb + (((2 * ki + (lr >> 1)) ^ (lc & 7)) << 3)] = pk;
      }
    }

    // O += P*V ; l (o1) += P*ones
#pragma unroll
    for (int kk = 0; kk < 2; kk++) {
      bf16x8 ap[2];
#pragma unroll
      for (int mi = 0; mi < 2; mi++)
        ap[mi] = *(const bf16x8*)&Ps[w * 2048 + (mi * 16 + lc) * 64 + (((kk * 4 + lr) ^ (lc & 7)) << 3)];
#pragma unroll
      for (int nj = 0; nj < 4; nj++) {
        const int row = nj * 16 + lc;
        bf16x8 bv = *(const bf16x8*)&Vt[row * 64 + (((kk * 4 + lr) ^ (row & 7)) << 3)];
#pragma unroll
        for (int mi = 0; mi < 2; mi++)
          o[mi][nj] = __builtin_amdgcn_mfma_f32_16x16x32_bf16(ap[mi], bv, o[mi][nj], 0, 0, 0);
      }
#pragma unroll
      for (int mi = 0; mi < 2; mi++)
        o1[mi] = __builtin_amdgcn_mfma_f32_16x16x32_bf16(ap[mi], ones, o1[mi], 0, 0, 0);
    }
    asm volatile("s_barrier" ::: "memory");
  }

  // epilogue: bf16 O-partial (undivided) + fp32 l-partial
  const int bb = plane >> 3, h = plane & 7;
  u16* Ob = Op + (long)split * 4194304;        // 8 MiB per split
#pragma unroll
  for (int mi = 0; mi < 2; mi++)
#pragma unroll
    for (int r = 0; r < 4; r++) {
      long t = qr0 + mi * 16 + 4 * lr + r;
#pragma unroll
      for (int nj = 0; nj < 4; nj++)
        Ob[(((long)(bb * 4096 + t) * 8 + h) << 6) + nj * 16 + lc] = f2bf(o[mi][nj][r]);
      if (lc == 0) lp[((split * 16 + plane) << 12) + t] = o1[mi][r];
    }
}

// ---------------- reduce: attnO = (O0+O1)/(l0+l1), in-place into Op0 ----------------
__global__ void reduce_kernel(u16* __restrict__ Op, const float* __restrict__ lp) {
  int i = blockIdx.x * 256 + threadIdx.x;      // 1048576 threads x 4 elems
  int row = i >> 7;                            // b*4096+t
  int c4 = (i & 127) << 2;                     // 0..508
  int h = c4 >> 6;
  int b = row >> 12, t = row & 4095;
  float l = lp[((b * 8 + h) << 12) + t] + lp[65536 + ((b * 8 + h) << 12) + t];
  float inv = 1.f / l;
  long idx = (long)row * 512 + c4;
  ushort4 a = *(const ushort4*)&Op[idx];
  ushort4 c = *(const ushort4*)&Op[4194304 + idx];
  ushort4 o;
  o.x = f2bf((bf2f(a.x) + bf2f(c.x)) * inv);
  o.y = f2bf((bf2f(a.y) + bf2f(c.y)) * inv);
  o.z = f2bf((bf2f(a.z) + bf2f(c.z)) * inv);
  o.w = f2bf((bf2f(a.w) + bf2f(c.w)) * inv);
  *(ushort4*)&Op[idx] = o;
}

// ---------------- out GEMM: out[8192,256] = attnO[8192,512] @ woT^T + bo ----------------
__global__ __launch_bounds__(256) void gemm_out(
    const u16* __restrict__ A, const u16* __restrict__ Bt, const float* __restrict__ bias,
    float* __restrict__ outf) {
  constexpr int K = 512;
  __shared__ __align__(16) u16 As[2][64 * 32];
  __shared__ __align__(16) u16 Bs[2][64 * 32];
  const int tid = threadIdx.x;
  const int lane = tid & 63, w = tid >> 6;
  const int wr = w >> 1, wc = w & 1;
  const int lr = lane >> 4, lc = lane & 15;
  const long tileM = (long)blockIdx.y * 64;
  const long tileN = (long)blockIdx.x * 64;

  f32x4 acc[2][2];
#pragma unroll
  for (int a = 0; a < 2; a++)
#pragma unroll
    for (int b = 0; b < 2; b++) acc[a][b] = (f32x4){0.f, 0.f, 0.f, 0.f};

  const int r0 = lane >> 2;
  const int blk = lane & 3;

  auto stage = [&](int buf, int k0) {
    int r = w * 16 + r0;
    int g = (blk ^ ((r >> 1) & 3)) << 3;
    async16(A + (tileM + r) * (long)K + k0 + g, (void*)&As[buf][(w * 16) * 32]);
    async16(Bt + (tileN + r) * (long)K + k0 + g, (void*)&Bs[buf][(w * 16) * 32]);
  };

  stage(0, 0);
  for (int k0 = 0; k0 < K; k0 += 32) {
    const int cur = (k0 >> 5) & 1;
    stage(cur ^ 1, (k0 + 32 < K) ? k0 + 32 : 0);
    asm volatile("s_waitcnt vmcnt(2)" ::: "memory");
    asm volatile("s_barrier" ::: "memory");

    bf16x8 af[2], bfv[2];
#pragma unroll
    for (int mi = 0; mi < 2; mi++) {
      int r = wr * 32 + mi * 16 + lc;
      af[mi] = *(const bf16x8*)&As[cur][r * 32 + ((lr ^ ((r >> 1) & 3)) << 3)];
    }
#pragma unroll
    for (int nj = 0; nj < 2; nj++) {
      int r = wc * 32 + nj * 16 + lc;
      bfv[nj] = *(const bf16x8*)&Bs[cur][r * 32 + ((lr ^ ((r >> 1) & 3)) << 3)];
    }
#pragma unroll
    for (int mi = 0; mi < 2; mi++)
#pragma unroll
      for (int nj = 0; nj < 2; nj++)
        acc[mi][nj] = __builtin_amdgcn_mfma_f32_16x16x32_bf16(af[mi], bfv[nj], acc[mi][nj], 0, 0, 0);
    asm volatile("s_barrier" ::: "memory");
  }

#pragma unroll
  for (int mi = 0; mi < 2; mi++)
#pragma unroll
    for (int nj = 0; nj < 2; nj++) {
      long col = tileN + wc * 32 + nj * 16 + lc;
      float bcol = bias[col];
      long row0 = tileM + wr * 32 + mi * 16 + lr * 4;
#pragma unroll
      for (int r = 0; r < 4; r++)
        outf[(row0 + r) * 256 + col] = acc[mi][nj][r] + bcol;
    }
}

// ---------------- launch ----------------
extern "C" void kernel_launch(void* const* d_in, const int* in_sizes, int n_in,
                              void* d_out, int out_size, void* d_ws, size_t ws_size,
                              hipStream_t stream) {
  const float* prompt = (const float*)d_in[0];
  const float* Wp = (const float*)d_in[1];
  const float* bp = (const float*)d_in[2];
  const float* Wqkv = (const float*)d_in[3];
  const float* bqkv = (const float*)d_in[4];
  const float* Wo = (const float*)d_in[5];
  const float* bo = (const float*)d_in[6];
  float* out = (float*)d_out;

  char* ws = (char*)d_ws;
  const size_t MiB = 1024 * 1024;
  u16* qb     = (u16*)(ws + 0);           // [b,h,t,d]  8 MiB
  u16* kb     = (u16*)(ws + 8 * MiB);     // [b,h,t,d]  8 MiB
  u16* vb     = (u16*)(ws + 16 * MiB);    // [b,h,d,t]  8 MiB (transposed)
  u16* pbf    = (u16*)(ws + 24 * MiB);    // [8192,256] bf16 4 MiB (dead after qkv)
  float* lpp  = (float*)(ws + 24 * MiB);  // [2][16][4096] fp32 512 KiB (overlays pbf)
  u16* Op     = (u16*)(ws + 28 * MiB);    // [2][b,t,h*d] bf16 partials, 2x8 MiB;
                                          // Op[0] becomes attnO after reduce
  u16* woT    = (u16*)(ws + 44 * MiB);                  // [256,512]  256 KiB
  u16* wfT    = (u16*)(ws + 44 * MiB + 256 * 1024);     // [1536,256] 768 KiB
  float* bfused = (float*)(ws + 45 * MiB);              // [1536] fp32

  prep_kernel<<<dim3(2680), dim3(256), 0, stream>>>(
      prompt, pbf, Wp, Wqkv, Wo, woT, bp, bqkv, bfused, wfT);

  // qkv = prompt @ Wfused + bfused -> q(scaled)/k [b,h,t,d], v^T [b,h,d,t]
  gemm_qkv<<<dim3(12, 64), dim3(256), 0, stream>>>(
      pbf, wfT, bfused, qb, kb, vb, 256);

  // flash attention, split-K=2 -> bf16 O-partials + fp32 l-partials
  flash_attn<<<dim3(32, 16, 2), dim3(256), 0, stream>>>(qb, kb, vb, Op, lpp);

  // combine partials in-place into Op[0] (== attnO [b,t,h*d])
  reduce_kernel<<<dim3(4096), dim3(256), 0, stream>>>(Op, lpp);

  // out = attn @ Wo + bo (fp32)
  gemm_out<<<dim3(4, 128), dim3(256), 0, stream>>>(Op, woT, bo, out);
}

// Round 12
// 188.911 us; speedup vs baseline: 1.2164x; 1.0982x over previous
//
#include <hip/hip_runtime.h>
#include <math.h>
#include <stdint.h>

// Transformer forward. R12 changes vs R11:
//  - Flash: 512-thread blocks (8 waves x 32q = 256 q/block), grid (16,16,2) =
//    512 blocks = EXACTLY 2/CU (R11's 1024 blocks at 3/CU capacity left a
//    256-block tail round killing the TLP gain). LDS = KV dbuf 32KB + Ps 32KB
//    = 64KB -> 16 waves/CU. Per-wave code unchanged (32q/wave kept).
//  - reduce kernel DELETED: merge (O0+O1)/(l0+l1) fused into gemm_out's
//    A-staging (VGPR path); B stays async16-DMA'd with vmcnt(1) prefetch.
//  - Keeps: merged prep (wf-GEMM + bias_fuse + Wo^T + prompt cvt), qkv GEMM,
//    split-K=2 flash with bf16 O-partials + fp32 l-partials, no-max exp2
//    softmax, ones-MFMA l, V transposed, S^T formulation.

typedef unsigned short u16;
typedef __attribute__((ext_vector_type(8))) __bf16 bf16x8;
typedef __attribute__((ext_vector_type(4))) __bf16 bf16x4;
typedef __attribute__((ext_vector_type(4))) float f32x4;

#define AS1 __attribute__((address_space(1)))
#define AS3 __attribute__((address_space(3)))

__device__ __forceinline__ void async16(const void* g, void* l) {
  __builtin_amdgcn_global_load_lds((const AS1 void*)g, (AS3 void*)l, 16, 0, 0);
}

__device__ __forceinline__ u16 f2bf(float f) {  // RNE fp32->bf16
  union { float f; unsigned u; } c; c.f = f;
  return (u16)((c.u + 0x7fffu + ((c.u >> 16) & 1u)) >> 16);
}

// ---------------- prep (one launch, block-range dispatch) ----------------
// [0,96):     wf GEMM  wfT[1536][256] = (Wp@Wqkv)^T, fp32 staged inline
// [96,120):   bias_fuse bfused[n] = bp@Wqkv[:,n] + bqkv[n]
// [120,632):  Wo [512][256] -> woT [256][512]
// [632,2680): prompt fp32 -> bf16 (524288 float4)
__global__ void prep_kernel(const float* __restrict__ prompt, u16* __restrict__ pbf,
                            const float* __restrict__ Wp, const float* __restrict__ Wqkv,
                            const float* __restrict__ Wo, u16* __restrict__ woT,
                            const float* __restrict__ bp, const float* __restrict__ bqkv,
                            float* __restrict__ bfused, u16* __restrict__ wfT) {
  __shared__ u16 Asf[64 * 40];
  __shared__ u16 Bsf[64 * 32];
  __shared__ float red[256];
  const int bid = blockIdx.x, tid = threadIdx.x;
  if (bid < 96) {                // wf GEMM: 4 k-tiles x 24 n-tiles of 64x64
    const int k0 = (bid & 3) * 64, n0 = (bid >> 2) * 64;
    const int lane = tid & 63, w = tid >> 6;
    const int wr = w >> 1, wc = w & 1;
    const int lr = lane >> 4, lc = lane & 15;
    f32x4 acc[2][2];
#pragma unroll
    for (int a = 0; a < 2; a++)
#pragma unroll
      for (int b = 0; b < 2; b++) acc[a][b] = (f32x4){0.f, 0.f, 0.f, 0.f};
    for (int e0 = 0; e0 < 512; e0 += 32) {
      {  // As[n][e] = bf16(Wqkv[e0+e][n0+n])
        const int er = tid >> 3, ng = (tid & 7) * 8;
        float4 v1 = *(const float4*)&Wqkv[(e0 + er) * 1536 + n0 + ng];
        float4 v2 = *(const float4*)&Wqkv[(e0 + er) * 1536 + n0 + ng + 4];
        Asf[(ng + 0) * 40 + er] = f2bf(v1.x); Asf[(ng + 1) * 40 + er] = f2bf(v1.y);
        Asf[(ng + 2) * 40 + er] = f2bf(v1.z); Asf[(ng + 3) * 40 + er] = f2bf(v1.w);
        Asf[(ng + 4) * 40 + er] = f2bf(v2.x); Asf[(ng + 5) * 40 + er] = f2bf(v2.y);
        Asf[(ng + 6) * 40 + er] = f2bf(v2.z); Asf[(ng + 7) * 40 + er] = f2bf(v2.w);
      }
      {  // Bs[k][e] = bf16(Wp[k0+k][e0+e])
        const int kr = tid >> 2, ec = (tid & 3) * 8;
        float4 w1 = *(const float4*)&Wp[(k0 + kr) * 512 + e0 + ec];
        float4 w2 = *(const float4*)&Wp[(k0 + kr) * 512 + e0 + ec + 4];
        u16 tmp[8] = {f2bf(w1.x), f2bf(w1.y), f2bf(w1.z), f2bf(w1.w),
                      f2bf(w2.x), f2bf(w2.y), f2bf(w2.z), f2bf(w2.w)};
        *(uint4*)&Bsf[kr * 32 + ec] = *(const uint4*)&tmp[0];
      }
      __syncthreads();
      bf16x8 af[2], bf2[2];
#pragma unroll
      for (int mi = 0; mi < 2; mi++)
        af[mi] = *(const bf16x8*)&Asf[(wr * 32 + mi * 16 + lc) * 40 + lr * 8];
#pragma unroll
      for (int nj = 0; nj < 2; nj++)
        bf2[nj] = *(const bf16x8*)&Bsf[(wc * 32 + nj * 16 + lc) * 32 + lr * 8];
#pragma unroll
      for (int mi = 0; mi < 2; mi++)
#pragma unroll
        for (int nj = 0; nj < 2; nj++)
          acc[mi][nj] = __builtin_amdgcn_mfma_f32_16x16x32_bf16(af[mi], bf2[nj], acc[mi][nj], 0, 0, 0);
      __syncthreads();
    }
#pragma unroll
    for (int mi = 0; mi < 2; mi++)
#pragma unroll
      for (int nj = 0; nj < 2; nj++)
#pragma unroll
        for (int r = 0; r < 4; r++)
          wfT[(n0 + wr * 32 + mi * 16 + 4 * lr + r) * 256 + k0 + wc * 32 + nj * 16 + lc] =
              f2bf(acc[mi][nj][r]);
  } else if (bid < 120) {        // bias fuse
    const int nloc = tid & 63, slice = tid >> 6;
    const int n = (bid - 96) * 64 + nloc;
    float s = 0.f;
#pragma unroll 8
    for (int e = slice * 128; e < slice * 128 + 128; e++) s += bp[e] * Wqkv[e * 1536 + n];
    red[tid] = s;
    __syncthreads();
    if (slice == 0)
      bfused[n] = red[nloc] + red[64 + nloc] + red[128 + nloc] + red[192 + nloc] + bqkv[n];
  } else if (bid < 632) {        // Wo^T
    int j = (bid - 120) * 256 + tid;
    int n = j >> 9, k = j & 511;
    woT[j] = f2bf(Wo[k * 256 + n]);
  } else {                       // prompt cvt
    int i = (bid - 632) * 256 + tid;
    float4 v = ((const float4*)prompt)[i];
    ushort4 o;
    o.x = f2bf(v.x); o.y = f2bf(v.y); o.z = f2bf(v.z); o.w = f2bf(v.w);
    ((ushort4*)pbf)[i] = o;
  }
}

// ---------------- qkv GEMM (unchanged) ----------------
__global__ __launch_bounds__(256) void gemm_qkv(
    const u16* __restrict__ A, const u16* __restrict__ Bt, const float* __restrict__ bias,
    u16* __restrict__ qO, u16* __restrict__ kO, u16* __restrict__ vO, int K) {
  constexpr int TM = 128, MI = 4, NJ = 4;
  __shared__ __align__(16) u16 As[2][TM * 32];
  __shared__ __align__(16) u16 Bs[2][TM * 32];
  const int tid = threadIdx.x;
  const int lane = tid & 63, w = tid >> 6;
  const int wr = w >> 1, wc = w & 1;
  const int lr = lane >> 4, lc = lane & 15;
  const long tileM = (long)blockIdx.y * 128;
  const long tileN = (long)blockIdx.x * 128;

  f32x4 acc[MI][NJ];
#pragma unroll
  for (int a = 0; a < MI; a++)
#pragma unroll
    for (int b = 0; b < NJ; b++) acc[a][b] = (f32x4){0.f, 0.f, 0.f, 0.f};

  const int r0 = lane >> 2;
  const int blk = lane & 3;

  auto stage = [&](int buf, int k0) {
#pragma unroll
    for (int i = 0; i < 2; i++) {
      int r = w * 32 + i * 16 + r0;
      int g = (blk ^ ((r >> 1) & 3)) << 3;
      async16(A + (tileM + r) * (long)K + k0 + g, (void*)&As[buf][(w * 32 + i * 16) * 32]);
      async16(Bt + (tileN + r) * (long)K + k0 + g, (void*)&Bs[buf][(w * 32 + i * 16) * 32]);
    }
  };

  stage(0, 0);
  for (int k0 = 0; k0 < K; k0 += 32) {
    const int cur = (k0 >> 5) & 1;
    stage(cur ^ 1, (k0 + 32 < K) ? k0 + 32 : 0);
    asm volatile("s_waitcnt vmcnt(4)" ::: "memory");
    asm volatile("s_barrier" ::: "memory");

    bf16x8 af[MI], bfv[NJ];
#pragma unroll
    for (int mi = 0; mi < MI; mi++) {
      int r = wr * 64 + mi * 16 + lc;
      af[mi] = *(const bf16x8*)&As[cur][r * 32 + ((lr ^ ((r >> 1) & 3)) << 3)];
    }
#pragma unroll
    for (int nj = 0; nj < NJ; nj++) {
      int r = wc * 64 + nj * 16 + lc;
      bfv[nj] = *(const bf16x8*)&Bs[cur][r * 32 + ((lr ^ ((r >> 1) & 3)) << 3)];
    }
#pragma unroll
    for (int mi = 0; mi < MI; mi++)
#pragma unroll
      for (int nj = 0; nj < NJ; nj++)
        acc[mi][nj] = __builtin_amdgcn_mfma_f32_16x16x32_bf16(af[mi], bfv[nj], acc[mi][nj], 0, 0, 0);
    asm volatile("s_barrier" ::: "memory");
  }

#pragma unroll
  for (int mi = 0; mi < MI; mi++)
#pragma unroll
    for (int nj = 0; nj < NJ; nj++) {
      long col = tileN + wc * 64 + nj * 16 + lc;
      float bcol = bias[col];
      long row0 = tileM + wr * 64 + mi * 16 + lr * 4;
      int sec = (int)(col >> 9);
      int c2 = (int)(col & 511);
      int h = c2 >> 6, d = c2 & 63;
      long pl = (row0 >> 12) * 8 + h;
      long t0 = row0 & 4095;
      if (sec == 2) {
        ushort4 pk;
        pk.x = f2bf(acc[mi][nj][0] + bcol);
        pk.y = f2bf(acc[mi][nj][1] + bcol);
        pk.z = f2bf(acc[mi][nj][2] + bcol);
        pk.w = f2bf(acc[mi][nj][3] + bcol);
        *(ushort4*)&vO[(pl * 64 + d) * 4096 + t0] = pk;
      } else {
        u16* dst = sec ? kO : qO;
        const float sc = sec ? 1.f : 0.18033688f;  // q: 1/8 * log2(e)
#pragma unroll
        for (int r = 0; r < 4; r++)
          dst[((pl * 4096 + t0 + r) << 6) + d] = f2bf((acc[mi][nj][r] + bcol) * sc);
      }
    }
}

// ---------------- flash attention (split-K=2, 512-thread blocks, 2/CU exact) ----------------
// Q,K bf16 [b*h,4096,64] (q pre-scaled by 0.125*log2e); VT bf16 [b*h,64,4096].
// Block (qtile, plane, split): 8 waves x 32 q = 256 q, 2048 keys, 32 KV64-iters.
// LDS: KV dbuf 32KB + Ps 32KB = 64KB -> 2 blocks/CU, 16 waves/CU.
// Writes bf16 O-partials (undivided) + fp32 l-partials.
__global__ __launch_bounds__(512) void flash_attn(
    const u16* __restrict__ Q, const u16* __restrict__ Kg,
    const u16* __restrict__ VTg, u16* __restrict__ Op, float* __restrict__ lp) {
  __shared__ __align__(16) u16 KV[2][8192];   // per buf: Ks[64*64] | Vt[64*64]
  __shared__ __align__(16) u16 Ps[8 * 2048];  // per-wave [32 q][64 key]

  const int tid = threadIdx.x, lane = tid & 63, w = tid >> 6;  // w in 0..7
  const int lr = lane >> 4, lc = lane & 15;
  const int plane = blockIdx.y;                // b*8+h
  const int split = blockIdx.z;                // 0/1: keys [0,2048) / [2048,4096)
  const long pbase = (long)plane << 18;        // *4096*64
  const int qr0 = blockIdx.x * 256 + w * 32;
  const int tj0 = split * 32;                  // first KV64 tile index

  bf16x8 bq[2][2];
#pragma unroll
  for (int qi = 0; qi < 2; qi++)
#pragma unroll
    for (int kk = 0; kk < 2; kk++)
      bq[qi][kk] = *(const bf16x8*)&Q[pbase + (long)(qr0 + qi * 16 + lc) * 64 + kk * 32 + lr * 8];

  bf16x8 ones;
#pragma unroll
  for (int u = 0; u < 8; u++) ones[u] = (__bf16)1.0f;

  f32x4 o[2][4], o1[2];
#pragma unroll
  for (int mi = 0; mi < 2; mi++) {
    o1[mi] = (f32x4){0.f, 0.f, 0.f, 0.f};
#pragma unroll
    for (int nj = 0; nj < 4; nj++) o[mi][nj] = (f32x4){0.f, 0.f, 0.f, 0.f};
  }

  const int krow = lane >> 3, kblk = lane & 7;   // 8 rows x 8 16B-blocks per inst

  auto stage = [&](int buf, int tj) {
    const u16* kS = Kg + pbase + (long)tj * 4096;
    const u16* vS = VTg + pbase + (long)tj * 64;
    int row = w * 8 + krow;
    async16(kS + (long)row * 64 + ((kblk ^ (row & 7)) << 3),
            (void*)&KV[buf][(w * 8) * 64]);
    async16(vS + (long)row * 4096 + ((kblk ^ (row & 7)) << 3),
            (void*)&KV[buf][4096 + (w * 8) * 64]);
  };

  stage(0, tj0);
  for (int j = 0; j < 32; j++) {
    const int cur = j & 1;
    stage(cur ^ 1, (j + 1 < 32) ? tj0 + j + 1 : tj0);  // j=31: dummy restage
    asm volatile("s_waitcnt vmcnt(2)" ::: "memory");
    asm volatile("s_barrier" ::: "memory");

    const u16* Ks = &KV[cur][0];
    const u16* Vt = &KV[cur][4096];

    // S^T tile: [64 key][32 q] per wave
    f32x4 s[4][2];
#pragma unroll
    for (int ki = 0; ki < 4; ki++)
#pragma unroll
      for (int qi = 0; qi < 2; qi++) s[ki][qi] = (f32x4){0.f, 0.f, 0.f, 0.f};
#pragma unroll
    for (int ki = 0; ki < 4; ki++) {
      const int row = ki * 16 + lc;
      bf16x8 ak[2];
#pragma unroll
      for (int kk = 0; kk < 2; kk++)
        ak[kk] = *(const bf16x8*)&Ks[row * 64 + (((kk * 4 + lr) ^ (row & 7)) << 3)];
#pragma unroll
      for (int qi = 0; qi < 2; qi++)
#pragma unroll
        for (int kk = 0; kk < 2; kk++)
          s[ki][qi] = __builtin_amdgcn_mfma_f32_16x16x32_bf16(ak[kk], bq[qi][kk], s[ki][qi], 0, 0, 0);
    }

    // p = exp2(s) -> Ps (per-wave; same-wave LDS W->R is in-order)
#pragma unroll
    for (int qi = 0; qi < 2; qi++) {
      const int pb = w * 2048 + (qi * 16 + lc) * 64 + 4 * (lr & 1);
#pragma unroll
      for (int ki = 0; ki < 4; ki++) {
        bf16x4 pk;
        pk[0] = (__bf16)__builtin_amdgcn_exp2f(s[ki][qi][0]);
        pk[1] = (__bf16)__builtin_amdgcn_exp2f(s[ki][qi][1]);
        pk[2] = (__bf16)__builtin_amdgcn_exp2f(s[ki][qi][2]);
        pk[3] = (__bf16)__builtin_amdgcn_exp2f(s[ki][qi][3]);
        *(bf16x4*)&Ps[pb + (((2 * ki + (lr >> 1)) ^ (lc & 7)) << 3)] = pk;
      }
    }

    // O += P*V ; l (o1) += P*ones
#pragma unroll
    for (int kk = 0; kk < 2; kk++) {
      bf16x8 ap[2];
#pragma unroll
      for (int mi = 0; mi < 2; mi++)
        ap[mi] = *(const bf16x8*)&Ps[w * 2048 + (mi * 16 + lc) * 64 + (((kk * 4 + lr) ^ (lc & 7)) << 3)];
#pragma unroll
      for (int nj = 0; nj < 4; nj++) {
        const int row = nj * 16 + lc;
        bf16x8 bv = *(const bf16x8*)&Vt[row * 64 + (((kk * 4 + lr) ^ (row & 7)) << 3)];
#pragma unroll
        for (int mi = 0; mi < 2; mi++)
          o[mi][nj] = __builtin_amdgcn_mfma_f32_16x16x32_bf16(ap[mi], bv, o[mi][nj], 0, 0, 0);
      }
#pragma unroll
      for (int mi = 0; mi < 2; mi++)
        o1[mi] = __builtin_amdgcn_mfma_f32_16x16x32_bf16(ap[mi], ones, o1[mi], 0, 0, 0);
    }
    asm volatile("s_barrier" ::: "memory");
  }

  // epilogue: bf16 O-partial (undivided) + fp32 l-partial
  const int bb = plane >> 3, h = plane & 7;
  u16* Ob = Op + (long)split * 4194304;        // 8 MiB per split
#pragma unroll
  for (int mi = 0; mi < 2; mi++)
#pragma unroll
    for (int r = 0; r < 4; r++) {
      long t = qr0 + mi * 16 + 4 * lr + r;
#pragma unroll
      for (int nj = 0; nj < 4; nj++)
        Ob[(((long)(bb * 4096 + t) * 8 + h) << 6) + nj * 16 + lc] = f2bf(o[mi][nj][r]);
      if (lc == 0) lp[((split * 16 + plane) << 12) + t] = o1[mi][r];
    }
}

// ---------------- out GEMM (+fused split-K merge): out = ((O0+O1)/l) @ woT^T + bo ----------------
// A staged through VGPRs: (O0+O1)*inv(l0+l1) -> bf16 -> LDS. B via async16 DMA.
__global__ __launch_bounds__(256) void gemm_out(
    const u16* __restrict__ Op, const float* __restrict__ lp,
    const u16* __restrict__ Bt, const float* __restrict__ bias,
    float* __restrict__ outf) {
  constexpr int K = 512;
  __shared__ __align__(16) u16 As[2][64 * 32];
  __shared__ __align__(16) u16 Bs[2][64 * 32];
  const int tid = threadIdx.x;
  const int lane = tid & 63, w = tid >> 6;
  const int wr = w >> 1, wc = w & 1;
  const int lr = lane >> 4, lc = lane & 15;
  const long tileM = (long)blockIdx.y * 64;
  const long tileN = (long)blockIdx.x * 64;

  f32x4 acc[2][2];
#pragma unroll
  for (int a = 0; a < 2; a++)
#pragma unroll
    for (int b = 0; b < 2; b++) acc[a][b] = (f32x4){0.f, 0.f, 0.f, 0.f};

  const int r0 = lane >> 2;
  const int blk = lane & 3;

  auto stageB = [&](int buf, int k0) {
    int r = w * 16 + r0;
    int g = (blk ^ ((r >> 1) & 3)) << 3;
    async16(Bt + (tileN + r) * (long)K + k0 + g, (void*)&Bs[buf][(w * 16) * 32]);
  };

  // A merge-staging geometry: thread covers row ar, 16B block ablk
  const int ar = tid >> 2, ablk = tid & 3;
  const long arow = tileM + ar;
  const int ab = (int)(arow >> 12), at = (int)(arow & 4095);

  auto stageA = [&](int buf, int k0) {
    int h = k0 >> 6;
    float l0 = lp[(long)((ab * 8 + h) << 12) + at];
    float l1 = lp[(long)((16 * 4096 * 4) + 0) + 0];  // placeholder (replaced below)
    (void)l1;
    float l = l0 + lp[(long)(((16 + ab * 8 + h)) << 12) + at];
    float inv = 1.f / l;
    long idx = arow * 512 + k0 + ablk * 8;
    bf16x8 v0 = *(const bf16x8*)&Op[idx];
    bf16x8 v1 = *(const bf16x8*)&Op[4194304 + idx];
    u16 tmp[8];
#pragma unroll
    for (int e = 0; e < 8; e++)
      tmp[e] = f2bf(((float)v0[e] + (float)v1[e]) * inv);
    *(uint4*)&As[buf][ar * 32 + ((ablk ^ ((ar >> 1) & 3)) << 3)] = *(const uint4*)&tmp[0];
  };

  stageB(0, 0);
  for (int k0 = 0; k0 < K; k0 += 32) {
    const int cur = (k0 >> 5) & 1;
    stageB(cur ^ 1, (k0 + 32 < K) ? k0 + 32 : 0);
    stageA(cur, k0);
    // drain A ds_writes + this tile's B DMA; leave next-B (1 inst) in flight
    asm volatile("s_waitcnt vmcnt(1) lgkmcnt(0)" ::: "memory");
    asm volatile("s_barrier" ::: "memory");

    bf16x8 af[2], bfv[2];
#pragma unroll
    for (int mi = 0; mi < 2; mi++) {
      int r = wr * 32 + mi * 16 + lc;
      af[mi] = *(const bf16x8*)&As[cur][r * 32 + ((lr ^ ((r >> 1) & 3)) << 3)];
    }
#pragma unroll
    for (int nj = 0; nj < 2; nj++) {
      int r = wc * 32 + nj * 16 + lc;
      bfv[nj] = *(const bf16x8*)&Bs[cur][r * 32 + ((lr ^ ((r >> 1) & 3)) << 3)];
    }
#pragma unroll
    for (int mi = 0; mi < 2; mi++)
#pragma unroll
      for (int nj = 0; nj < 2; nj++)
        acc[mi][nj] = __builtin_amdgcn_mfma_f32_16x16x32_bf16(af[mi], bfv[nj], acc[mi][nj], 0, 0, 0);
    asm volatile("s_barrier" ::: "memory");
  }

#pragma unroll
  for (int mi = 0; mi < 2; mi++)
#pragma unroll
    for (int nj = 0; nj < 2; nj++) {
      long col = tileN + wc * 32 + nj * 16 + lc;
      float bcol = bias[col];
      long row0 = tileM + wr * 32 + mi * 16 + lr * 4;
#pragma unroll
      for (int r = 0; r < 4; r++)
        outf[(row0 + r) * 256 + col] = acc[mi][nj][r] + bcol;
    }
}

// ---------------- launch ----------------
extern "C" void kernel_launch(void* const* d_in, const int* in_sizes, int n_in,
                              void* d_out, int out_size, void* d_ws, size_t ws_size,
                              hipStream_t stream) {
  const float* prompt = (const float*)d_in[0];
  const float* Wp = (const float*)d_in[1];
  const float* bp = (const float*)d_in[2];
  const float* Wqkv = (const float*)d_in[3];
  const float* bqkv = (const float*)d_in[4];
  const float* Wo = (const float*)d_in[5];
  const float* bo = (const float*)d_in[6];
  float* out = (float*)d_out;

  char* ws = (char*)d_ws;
  const size_t MiB = 1024 * 1024;
  u16* qb     = (u16*)(ws + 0);           // [b,h,t,d]  8 MiB
  u16* kb     = (u16*)(ws + 8 * MiB);     // [b,h,t,d]  8 MiB
  u16* vb     = (u16*)(ws + 16 * MiB);    // [b,h,d,t]  8 MiB (transposed)
  u16* pbf    = (u16*)(ws + 24 * MiB);    // [8192,256] bf16 4 MiB (dead after qkv)
  float* lpp  = (float*)(ws + 24 * MiB);  // [2][16][4096] fp32 512 KiB (overlays pbf)
  u16* Op     = (u16*)(ws + 28 * MiB);    // [2][b,t,h*d] bf16 partials, 2x8 MiB
  u16* woT    = (u16*)(ws + 44 * MiB);                  // [256,512]  256 KiB
  u16* wfT    = (u16*)(ws + 44 * MiB + 256 * 1024);     // [1536,256] 768 KiB
  float* bfused = (float*)(ws + 45 * MiB);              // [1536] fp32

  prep_kernel<<<dim3(2680), dim3(256), 0, stream>>>(
      prompt, pbf, Wp, Wqkv, Wo, woT, bp, bqkv, bfused, wfT);

  // qkv = prompt @ Wfused + bfused -> q(scaled)/k [b,h,t,d], v^T [b,h,d,t]
  gemm_qkv<<<dim3(12, 64), dim3(256), 0, stream>>>(
      pbf, wfT, bfused, qb, kb, vb, 256);

  // flash attention, split-K=2, 512-thread blocks -> O-partials + l-partials
  flash_attn<<<dim3(16, 16, 2), dim3(512), 0, stream>>>(qb, kb, vb, Op, lpp);

  // out = ((O0+O1)/(l0+l1)) @ Wo + bo  (merge fused into A-staging)
  gemm_out<<<dim3(4, 128), dim3(256), 0, stream>>>(Op, lpp, woT, bo, out);
}